// Round 14
// baseline (115.266 us; speedup 1.0000x reference)
//
#include <hip/hip_runtime.h>

#define NN 4096
#define NE 131072
#define CH 256
#define KSEL 2048

// ===== K0: zero B8 (blocks 0..2047) + zero rowcnt/cursor/d2f 48KB (blocks 2048..2059) =====
__global__ void k0_zero(uint4* __restrict__ B8v, uint4* __restrict__ small) {
    int b = blockIdx.x;
    int t = threadIdx.x;
    if (b < 2048) {
        B8v[b * 256 + t] = uint4{0u, 0u, 0u, 0u};
    } else {
        small[(b - 2048) * 256 + t] = uint4{0u, 0u, 0u, 0u};
    }
}

// ===== K1: out-degree count =====
__global__ void k1_count(const int* __restrict__ ei, int* __restrict__ rowcnt) {
    int e = blockIdx.x * blockDim.x + threadIdx.x;
    atomicAdd(&rowcnt[ei[e]], 1);
}

// ===== K2: exclusive prefix sum of rowcnt[4096] -> rowptr[4097] (single block) =====
__global__ __launch_bounds__(256) void prefix4096(const int* __restrict__ cnt,
                                                  int* __restrict__ ptr) {
    __shared__ int psum[256];
    int t = threadIdx.x;
    int loc[16];
    int s = 0;
    #pragma unroll
    for (int i = 0; i < 16; i++) { loc[i] = s; s += cnt[t * 16 + i]; }
    psum[t] = s;
    __syncthreads();
    if (t == 0) {
        int run = 0;
        for (int i = 0; i < 256; i++) { int v = psum[i]; psum[i] = run; run += v; }
        ptr[4096] = run;
    }
    __syncthreads();
    int off = psum[t];
    #pragma unroll
    for (int i = 0; i < 16; i++) ptr[t * 16 + i] = off + loc[i];
}

// ===== K3: scatter edges into CSR + accumulate d2[r] += rowcnt[c] =====
__global__ void k3_scatter_d2(const int* __restrict__ ei, const int* __restrict__ rowptr,
                              int* __restrict__ cursor, int* __restrict__ colidx,
                              const int* __restrict__ rowcnt, float* __restrict__ d2f) {
    int e = blockIdx.x * blockDim.x + threadIdx.x;
    int r = ei[e];
    int c = ei[NE + e];
    int p = atomicAdd(&cursor[r], 1);
    colidx[rowptr[r] + p] = c;
    atomicAdd(&d2f[r], (float)rowcnt[c]);
}

// ===== K4: score = tanh(pw0*(x.tr) + pw1*deg); d3 inline via CSR gather =====
__global__ __launch_bounds__(256) void k4_score(const float* __restrict__ x,
                                                const float* __restrict__ tr,
                                                const int* __restrict__ rowcnt,
                                                const float* __restrict__ d2f,
                                                const int* __restrict__ rowptr,
                                                const int* __restrict__ colidx,
                                                const float* __restrict__ fw,
                                                const float* __restrict__ pw,
                                                float* __restrict__ score) {
    int gtid = blockIdx.x * blockDim.x + threadIdx.x;
    int node = gtid >> 6;
    int lane = gtid & 63;
    const float* xr = x + (size_t)node * CH;
    float s = 0.f;
    #pragma unroll
    for (int q = 0; q < CH; q += 64) s += xr[q + lane] * tr[q + lane];
    int rs = rowptr[node], re = rowptr[node + 1];
    float dd = 0.f;                      // d3[node] = sum_{k in adj(node)} d2[k]
    for (int j = rs + lane; j < re; j += 64) dd += d2f[colidx[j]];
    #pragma unroll
    for (int off = 32; off > 0; off >>= 1) {
        s += __shfl_down(s, off);
        dd += __shfl_down(dd, off);
    }
    if (lane == 0) {
        float deg = fw[0] + fw[1] * (float)rowcnt[node] + fw[2] * d2f[node] + fw[3] * dd;
        score[node] = tanhf(pw[0] * s + pw[1] * deg);
    }
}

// ===== K5: stable descending argsort rank (== jnp stable argsort(-s)) =====
__global__ __launch_bounds__(256) void rank_kernel(const float* __restrict__ score,
                                                   int* __restrict__ rnk,
                                                   int* __restrict__ perm,
                                                   float* __restrict__ score_perm,
                                                   float* __restrict__ out_perm,
                                                   float* __restrict__ out_score) {
    __shared__ int wsum[4];
    int i = blockIdx.x;
    int t = threadIdx.x;
    float si = score[i];
    int cnt = 0;
    #pragma unroll
    for (int it = 0; it < NN / 4 / 256; it++) {
        int j4 = it * 256 + t;
        float4 s4 = reinterpret_cast<const float4*>(score)[j4];
        int j = j4 * 4;
        cnt += (int)((s4.x > si) | ((s4.x == si) & (j + 0 < i)));
        cnt += (int)((s4.y > si) | ((s4.y == si) & (j + 1 < i)));
        cnt += (int)((s4.z > si) | ((s4.z == si) & (j + 2 < i)));
        cnt += (int)((s4.w > si) | ((s4.w == si) & (j + 3 < i)));
    }
    #pragma unroll
    for (int off = 32; off > 0; off >>= 1) cnt += __shfl_down(cnt, off);
    if ((t & 63) == 0) wsum[t >> 6] = cnt;
    __syncthreads();
    if (t == 0) {
        int r = wsum[0] + wsum[1] + wsum[2] + wsum[3];
        rnk[i] = r;
        if (r < KSEL) {
            perm[r] = i;
            score_perm[r] = si;
            out_perm[r] = (float)i;
            out_score[r] = si;
        }
    }
}

// ===== K6: build B8[u,c]=A[u,perm[c]] (blocks 0..511) + xout (blocks 512..2559) =====
__global__ void k6_b8_xout(const int* __restrict__ ei, const int* __restrict__ rnk,
                           unsigned int* __restrict__ B32, const float* __restrict__ x,
                           const int* __restrict__ perm, const float* __restrict__ score_perm,
                           float* __restrict__ out_x) {
    int b = blockIdx.x;
    int t = threadIdx.x;
    if (b < 512) {
        int e = b * 256 + t;
        int rv = rnk[ei[NE + e]];
        if (rv < KSEL) {
            size_t idx = (size_t)ei[e] * KSEL + rv;
            atomicAdd(&B32[idx >> 2], 1u << ((idx & 3) * 8));
        }
    } else {
        int r = b - 512;
        out_x[(size_t)r * CH + t] = x[(size_t)perm[r] * CH + t] * score_perm[r];
    }
}

// ===== K7: B2[u,:] = sum_{k in adj(u)} B8[k,:]  — XCD-partitioned column tiles =====
// c_tile = bx & 3: with round-robin block->XCD dispatch, each XCD touches one
// 2MB column slice of B8 -> L2-resident. One wave per row (CSR loads wave-uniform).
__global__ __launch_bounds__(256) void build_B2(const int* __restrict__ rowptr,
                                                const int* __restrict__ colidx,
                                                const unsigned char* __restrict__ B8,
                                                unsigned char* __restrict__ B2) {
    int bx = blockIdx.x;            // 2048 blocks
    int ct = bx & 3;                // 512B column tile
    int u0 = (bx >> 2) * 8;         // 8 rows per block
    int t = threadIdx.x;
    int sg = t >> 6;                // wave id (4 waves)
    int lane = t & 63;
    int cb = ct * 512 + lane * 8;   // byte offset within row
    #pragma unroll
    for (int ui = 0; ui < 2; ui++) {
        int u = u0 + sg * 2 + ui;
        int s = rowptr[u], e = rowptr[u + 1];
        unsigned sx = 0, sy = 0;    // packed byte lanes (totals <= 255, exact)
        for (int j = s; j < e; j++) {
            int k = colidx[j];
            uint2 v = *(const uint2*)(B8 + (size_t)k * KSEL + cb);
            sx += v.x;
            sy += v.y;
        }
        *(uint2*)(B2 + (size_t)u * KSEL + cb) = uint2{sx, sy};
    }
}

// ===== K8: M_pool row r = w3*sum_{k in adj(pr)} B2[k,:] + w2*B2[pr,:] + w1*B8[pr,:] + w0*I =====
// Same XCD column-tile partitioning; u16x2-packed accumulation (A^3 <= ~15K < 65535).
__global__ __launch_bounds__(256) void mpool_kernel(const int* __restrict__ rowptr,
                                                    const int* __restrict__ colidx,
                                                    const unsigned char* __restrict__ B8,
                                                    const unsigned char* __restrict__ B2,
                                                    const int* __restrict__ perm,
                                                    const float* __restrict__ fw,
                                                    float* __restrict__ Mpool) {
    int bx = blockIdx.x;            // 1024 blocks
    int ct = bx & 3;
    int r0 = (bx >> 2) * 8;
    int t = threadIdx.x;
    int sg = t >> 6;
    int lane = t & 63;
    int cb = ct * 512 + lane * 8;   // byte offset == starting column index
    float w0 = fw[0], w1 = fw[1], w2 = fw[2], w3 = fw[3];
    #pragma unroll
    for (int ri = 0; ri < 2; ri++) {
        int r = r0 + sg * 2 + ri;
        int pr = perm[r];
        int s = rowptr[pr], e = rowptr[pr + 1];
        unsigned a0 = 0, a1 = 0, a2 = 0, a3 = 0;
        for (int j = s; j < e; j++) {
            int k = colidx[j];
            uint2 v = *(const uint2*)(B2 + (size_t)k * KSEL + cb);
            a0 += v.x & 0x00FF00FFu;
            a1 += (v.x >> 8) & 0x00FF00FFu;
            a2 += v.y & 0x00FF00FFu;
            a3 += (v.y >> 8) & 0x00FF00FFu;
        }
        int sum[8];
        sum[0] = a0 & 0xFFFF; sum[2] = a0 >> 16;
        sum[1] = a1 & 0xFFFF; sum[3] = a1 >> 16;
        sum[4] = a2 & 0xFFFF; sum[6] = a2 >> 16;
        sum[5] = a3 & 0xFFFF; sum[7] = a3 >> 16;
        uint2 v2 = *(const uint2*)(B2 + (size_t)pr * KSEL + cb);
        uint2 v1 = *(const uint2*)(B8 + (size_t)pr * KSEL + cb);
        int b2[8], b1[8];
        b2[0] = v2.x & 255;         b2[1] = (v2.x >> 8) & 255;
        b2[2] = (v2.x >> 16) & 255; b2[3] = v2.x >> 24;
        b2[4] = v2.y & 255;         b2[5] = (v2.y >> 8) & 255;
        b2[6] = (v2.y >> 16) & 255; b2[7] = v2.y >> 24;
        b1[0] = v1.x & 255;         b1[1] = (v1.x >> 8) & 255;
        b1[2] = (v1.x >> 16) & 255; b1[3] = v1.x >> 24;
        b1[4] = v1.y & 255;         b1[5] = (v1.y >> 8) & 255;
        b1[6] = (v1.y >> 16) & 255; b1[7] = v1.y >> 24;
        float o[8];
        #pragma unroll
        for (int j = 0; j < 8; j++) {
            o[j] = w3 * (float)sum[j] + w2 * (float)b2[j] + w1 * (float)b1[j]
                 + ((cb + j) == r ? w0 : 0.f);
        }
        float* dst = Mpool + (size_t)r * KSEL + cb;
        *(float4*)dst = float4{o[0], o[1], o[2], o[3]};
        *(float4*)(dst + 4) = float4{o[4], o[5], o[6], o[7]};
    }
}

extern "C" void kernel_launch(void* const* d_in, const int* in_sizes, int n_in,
                              void* d_out, int out_size, void* d_ws, size_t ws_size,
                              hipStream_t stream) {
    const float* x  = (const float*)d_in[0];
    const int*   ei = (const int*)d_in[1];
    const float* tr = (const float*)d_in[2];
    const float* fw = (const float*)d_in[3];
    const float* pw = (const float*)d_in[4];

    float* out       = (float*)d_out;
    float* out_x     = out;
    float* out_M     = out + (size_t)KSEL * CH;
    float* out_perm  = out_M + (size_t)KSEL * KSEL;
    float* out_score = out_perm + KSEL;

    char* ws = (char*)d_ws;
    int*   rowcnt     = (int*)(ws);            // 16KB (zeroed by k0)
    int*   cursor     = (int*)(ws + 16384);    // 16KB (zeroed by k0)
    float* d2f        = (float*)(ws + 32768);  // 16KB (zeroed by k0)
    float* score      = (float*)(ws + 65536);
    int*   rnk        = (int*)(ws + 81920);
    int*   perm       = (int*)(ws + 98304);    // 8KB
    float* score_perm = (float*)(ws + 106496); // 8KB
    int*   rowptr     = (int*)(ws + 131072);   // 4097 ints (32KB slot)
    int*   colidx     = (int*)(ws + 163840);   // 512KB
    unsigned char* B8 = (unsigned char*)(ws + 1048576);   // [1MB, 9MB)
    unsigned char* B2 = (unsigned char*)(ws + 9437184);   // [9MB, 17MB)

    k0_zero<<<2060, 256, 0, stream>>>((uint4*)B8, (uint4*)rowcnt);
    k1_count<<<512, 256, 0, stream>>>(ei, rowcnt);
    prefix4096<<<1, 256, 0, stream>>>(rowcnt, rowptr);
    k3_scatter_d2<<<512, 256, 0, stream>>>(ei, rowptr, cursor, colidx, rowcnt, d2f);
    k4_score<<<1024, 256, 0, stream>>>(x, tr, rowcnt, d2f, rowptr, colidx, fw, pw, score);
    rank_kernel<<<NN, 256, 0, stream>>>(score, rnk, perm, score_perm, out_perm, out_score);
    k6_b8_xout<<<2560, 256, 0, stream>>>(ei, rnk, (unsigned int*)B8, x, perm, score_perm, out_x);
    build_B2<<<2048, 256, 0, stream>>>(rowptr, colidx, B8, B2);
    mpool_kernel<<<1024, 256, 0, stream>>>(rowptr, colidx, B8, B2, perm, fw, out_M);
}

// Round 15
// 110.581 us; speedup vs baseline: 1.0424x; 1.0424x over previous
//
#include <hip/hip_runtime.h>

#define NN 4096
#define NE 131072
#define CH 256
#define KSEL 2048

// ===== K1: zero B8 (blocks 0..2047) + count edges (blocks 2048..2559) =====
// (rowcnt/cursor/d2f zeroed by the async memset issued before this kernel)
__global__ void k1_zero_count(const int* __restrict__ ei, uint4* __restrict__ B8v,
                              int* __restrict__ rowcnt) {
    int b = blockIdx.x;
    int t = threadIdx.x;
    if (b < 2048) {
        B8v[b * 256 + t] = uint4{0u, 0u, 0u, 0u};
    } else {
        int e = (b - 2048) * 256 + t;
        atomicAdd(&rowcnt[ei[e]], 1);
    }
}

// ===== K2: exclusive prefix sum of rowcnt[4096] -> rowptr[4097] (single block) =====
__global__ __launch_bounds__(256) void prefix4096(const int* __restrict__ cnt,
                                                  int* __restrict__ ptr) {
    __shared__ int psum[256];
    int t = threadIdx.x;
    int loc[16];
    int s = 0;
    #pragma unroll
    for (int i = 0; i < 16; i++) { loc[i] = s; s += cnt[t * 16 + i]; }
    psum[t] = s;
    __syncthreads();
    if (t == 0) {
        int run = 0;
        for (int i = 0; i < 256; i++) { int v = psum[i]; psum[i] = run; run += v; }
        ptr[4096] = run;
    }
    __syncthreads();
    int off = psum[t];
    #pragma unroll
    for (int i = 0; i < 16; i++) ptr[t * 16 + i] = off + loc[i];
}

// ===== K3: scatter edges into CSR + accumulate d2[r] += rowcnt[c] =====
__global__ void k3_scatter_d2(const int* __restrict__ ei, const int* __restrict__ rowptr,
                              int* __restrict__ cursor, int* __restrict__ colidx,
                              const int* __restrict__ rowcnt, float* __restrict__ d2f) {
    int e = blockIdx.x * blockDim.x + threadIdx.x;
    int r = ei[e];
    int c = ei[NE + e];
    int p = atomicAdd(&cursor[r], 1);
    colidx[rowptr[r] + p] = c;
    atomicAdd(&d2f[r], (float)rowcnt[c]);
}

// ===== K4: score = tanh(pw0*(x.tr) + pw1*deg); d3 inline via CSR gather =====
__global__ __launch_bounds__(256) void k4_score(const float* __restrict__ x,
                                                const float* __restrict__ tr,
                                                const int* __restrict__ rowcnt,
                                                const float* __restrict__ d2f,
                                                const int* __restrict__ rowptr,
                                                const int* __restrict__ colidx,
                                                const float* __restrict__ fw,
                                                const float* __restrict__ pw,
                                                float* __restrict__ score) {
    int gtid = blockIdx.x * blockDim.x + threadIdx.x;
    int node = gtid >> 6;
    int lane = gtid & 63;
    const float* xr = x + (size_t)node * CH;
    float s = 0.f;
    #pragma unroll
    for (int q = 0; q < CH; q += 64) s += xr[q + lane] * tr[q + lane];
    int rs = rowptr[node], re = rowptr[node + 1];
    float dd = 0.f;                      // d3[node] = sum_{k in adj(node)} d2[k]
    for (int j = rs + lane; j < re; j += 64) dd += d2f[colidx[j]];
    #pragma unroll
    for (int off = 32; off > 0; off >>= 1) {
        s += __shfl_down(s, off);
        dd += __shfl_down(dd, off);
    }
    if (lane == 0) {
        float deg = fw[0] + fw[1] * (float)rowcnt[node] + fw[2] * d2f[node] + fw[3] * dd;
        score[node] = tanhf(pw[0] * s + pw[1] * deg);
    }
}

// ===== K5: stable descending argsort rank (== jnp stable argsort(-s)) =====
__global__ __launch_bounds__(256) void rank_kernel(const float* __restrict__ score,
                                                   int* __restrict__ rnk,
                                                   int* __restrict__ perm,
                                                   float* __restrict__ score_perm,
                                                   float* __restrict__ out_perm,
                                                   float* __restrict__ out_score) {
    __shared__ int wsum[4];
    int i = blockIdx.x;
    int t = threadIdx.x;
    float si = score[i];
    int cnt = 0;
    #pragma unroll
    for (int it = 0; it < NN / 4 / 256; it++) {
        int j4 = it * 256 + t;
        float4 s4 = reinterpret_cast<const float4*>(score)[j4];
        int j = j4 * 4;
        cnt += (int)((s4.x > si) | ((s4.x == si) & (j + 0 < i)));
        cnt += (int)((s4.y > si) | ((s4.y == si) & (j + 1 < i)));
        cnt += (int)((s4.z > si) | ((s4.z == si) & (j + 2 < i)));
        cnt += (int)((s4.w > si) | ((s4.w == si) & (j + 3 < i)));
    }
    #pragma unroll
    for (int off = 32; off > 0; off >>= 1) cnt += __shfl_down(cnt, off);
    if ((t & 63) == 0) wsum[t >> 6] = cnt;
    __syncthreads();
    if (t == 0) {
        int r = wsum[0] + wsum[1] + wsum[2] + wsum[3];
        rnk[i] = r;
        if (r < KSEL) {
            perm[r] = i;
            score_perm[r] = si;
            out_perm[r] = (float)i;
            out_score[r] = si;
        }
    }
}

// ===== K6: build B8[u,c]=A[u,perm[c]] (blocks 0..511) + xout (blocks 512..2559) =====
__global__ void k6_b8_xout(const int* __restrict__ ei, const int* __restrict__ rnk,
                           unsigned int* __restrict__ B32, const float* __restrict__ x,
                           const int* __restrict__ perm, const float* __restrict__ score_perm,
                           float* __restrict__ out_x) {
    int b = blockIdx.x;
    int t = threadIdx.x;
    if (b < 512) {
        int e = b * 256 + t;
        int rv = rnk[ei[NE + e]];
        if (rv < KSEL) {
            size_t idx = (size_t)ei[e] * KSEL + rv;
            atomicAdd(&B32[idx >> 2], 1u << ((idx & 3) * 8));
        }
    } else {
        int r = b - 512;
        out_x[(size_t)r * CH + t] = x[(size_t)perm[r] * CH + t] * score_perm[r];
    }
}

// ===== K7: B2[u,:] = sum_{k in adj(u)} B8[k,:] — 2 rows/block, uint4 loads =====
// Threads 0..127 (waves 0,1) -> row 2b; threads 128..255 (waves 2,3) -> row 2b+1.
// Wave-uniform CSR walk; per iteration a wave reads a contiguous 1KB row segment.
// Packed byte-lane adds exact (totals <= 255, proven rounds 9-14).
__global__ __launch_bounds__(256) void build_B2(const int* __restrict__ rowptr,
                                                const int* __restrict__ colidx,
                                                const unsigned char* __restrict__ B8,
                                                unsigned char* __restrict__ B2) {
    int t = threadIdx.x;
    int u = blockIdx.x * 2 + (t >> 7);
    int cb = (t & 127) * 16;            // byte offset within the 2KB row
    int s = rowptr[u], e = rowptr[u + 1];
    unsigned ax = 0, ay = 0, az = 0, aw = 0;
    for (int j = s; j < e; j++) {
        int k = colidx[j];
        uint4 v = *(const uint4*)(B8 + (size_t)k * KSEL + cb);
        ax += v.x; ay += v.y; az += v.z; aw += v.w;
    }
    *(uint4*)(B2 + (size_t)u * KSEL + cb) = uint4{ax, ay, az, aw};
}

// ===== K8: M_pool row r = w3*sum_{k in adj(pr)} B2[k,:] + w2*B2[pr,:] + w1*B8[pr,:] + w0*I =====
// Same 2-rows/block uint4 structure; u16x2-packed accumulation (A^3 <= ~15K < 65535).
__global__ __launch_bounds__(256) void mpool_kernel(const int* __restrict__ rowptr,
                                                    const int* __restrict__ colidx,
                                                    const unsigned char* __restrict__ B8,
                                                    const unsigned char* __restrict__ B2,
                                                    const int* __restrict__ perm,
                                                    const float* __restrict__ fw,
                                                    float* __restrict__ Mpool) {
    int t = threadIdx.x;
    int r = blockIdx.x * 2 + (t >> 7);
    int cb = (t & 127) * 16;            // byte offset == starting column index
    int pr = perm[r];
    int s = rowptr[pr], e = rowptr[pr + 1];
    unsigned a0 = 0, a1 = 0, a2 = 0, a3 = 0, a4 = 0, a5 = 0, a6 = 0, a7 = 0;
    for (int j = s; j < e; j++) {
        int k = colidx[j];
        uint4 v = *(const uint4*)(B2 + (size_t)k * KSEL + cb);
        a0 += v.x & 0x00FF00FFu; a1 += (v.x >> 8) & 0x00FF00FFu;
        a2 += v.y & 0x00FF00FFu; a3 += (v.y >> 8) & 0x00FF00FFu;
        a4 += v.z & 0x00FF00FFu; a5 += (v.z >> 8) & 0x00FF00FFu;
        a6 += v.w & 0x00FF00FFu; a7 += (v.w >> 8) & 0x00FF00FFu;
    }
    int sum[16];
    sum[0]  = a0 & 0xFFFF; sum[2]  = a0 >> 16;
    sum[1]  = a1 & 0xFFFF; sum[3]  = a1 >> 16;
    sum[4]  = a2 & 0xFFFF; sum[6]  = a2 >> 16;
    sum[5]  = a3 & 0xFFFF; sum[7]  = a3 >> 16;
    sum[8]  = a4 & 0xFFFF; sum[10] = a4 >> 16;
    sum[9]  = a5 & 0xFFFF; sum[11] = a5 >> 16;
    sum[12] = a6 & 0xFFFF; sum[14] = a6 >> 16;
    sum[13] = a7 & 0xFFFF; sum[15] = a7 >> 16;
    uint4 v2 = *(const uint4*)(B2 + (size_t)pr * KSEL + cb);
    uint4 v1 = *(const uint4*)(B8 + (size_t)pr * KSEL + cb);
    const unsigned* w2v = &v2.x;
    const unsigned* w1v = &v1.x;
    float w0 = fw[0], w1 = fw[1], w2 = fw[2], w3 = fw[3];
    float o[16];
    #pragma unroll
    for (int w = 0; w < 4; w++) {
        unsigned b2w = w2v[w], b1w = w1v[w];
        #pragma unroll
        for (int bq = 0; bq < 4; bq++) {
            int j = w * 4 + bq;
            float b2f = (float)((b2w >> (bq * 8)) & 255);
            float b1f = (float)((b1w >> (bq * 8)) & 255);
            o[j] = w3 * (float)sum[j] + w2 * b2f + w1 * b1f
                 + ((cb + j) == r ? w0 : 0.f);
        }
    }
    float* dst = Mpool + (size_t)r * KSEL + cb;
    *(float4*)dst        = float4{o[0],  o[1],  o[2],  o[3]};
    *(float4*)(dst + 4)  = float4{o[4],  o[5],  o[6],  o[7]};
    *(float4*)(dst + 8)  = float4{o[8],  o[9],  o[10], o[11]};
    *(float4*)(dst + 12) = float4{o[12], o[13], o[14], o[15]};
}

extern "C" void kernel_launch(void* const* d_in, const int* in_sizes, int n_in,
                              void* d_out, int out_size, void* d_ws, size_t ws_size,
                              hipStream_t stream) {
    const float* x  = (const float*)d_in[0];
    const int*   ei = (const int*)d_in[1];
    const float* tr = (const float*)d_in[2];
    const float* fw = (const float*)d_in[3];
    const float* pw = (const float*)d_in[4];

    float* out       = (float*)d_out;
    float* out_x     = out;
    float* out_M     = out + (size_t)KSEL * CH;
    float* out_perm  = out_M + (size_t)KSEL * KSEL;
    float* out_score = out_perm + KSEL;

    char* ws = (char*)d_ws;
    int*   rowcnt     = (int*)(ws);            // 16KB (zeroed)
    int*   cursor     = (int*)(ws + 16384);    // 16KB (zeroed)
    float* d2f        = (float*)(ws + 32768);  // 16KB (zeroed)
    float* score      = (float*)(ws + 65536);
    int*   rnk        = (int*)(ws + 81920);
    int*   perm       = (int*)(ws + 98304);    // 8KB
    float* score_perm = (float*)(ws + 106496); // 8KB
    int*   rowptr     = (int*)(ws + 131072);   // 4097 ints (32KB slot)
    int*   colidx     = (int*)(ws + 163840);   // 512KB
    unsigned char* B8 = (unsigned char*)(ws + 1048576);   // [1MB, 9MB)
    unsigned char* B2 = (unsigned char*)(ws + 9437184);   // [9MB, 17MB)

    (void)hipMemsetAsync(rowcnt, 0, 49152, stream);   // rowcnt, cursor, d2f

    k1_zero_count<<<2560, 256, 0, stream>>>(ei, (uint4*)B8, rowcnt);
    prefix4096<<<1, 256, 0, stream>>>(rowcnt, rowptr);
    k3_scatter_d2<<<512, 256, 0, stream>>>(ei, rowptr, cursor, colidx, rowcnt, d2f);
    k4_score<<<1024, 256, 0, stream>>>(x, tr, rowcnt, d2f, rowptr, colidx, fw, pw, score);
    rank_kernel<<<NN, 256, 0, stream>>>(score, rnk, perm, score_perm, out_perm, out_score);
    k6_b8_xout<<<2560, 256, 0, stream>>>(ei, rnk, (unsigned int*)B8, x, perm, score_perm, out_x);
    build_B2<<<2048, 256, 0, stream>>>(rowptr, colidx, B8, B2);
    mpool_kernel<<<1024, 256, 0, stream>>>(rowptr, colidx, B8, B2, perm, fw, out_M);
}

// Round 16
// 104.113 us; speedup vs baseline: 1.1071x; 1.0621x over previous
//
#include <hip/hip_runtime.h>

#define NN 4096
#define NE 131072
#define CH 256
#define KSEL 2048

// ===== K1: zero B8 (blocks 0..2047) + count edges (blocks 2048..2559) =====
__global__ void k1_zero_count(const int* __restrict__ ei, uint4* __restrict__ B8v,
                              int* __restrict__ rowcnt) {
    int b = blockIdx.x;
    int t = threadIdx.x;
    if (b < 2048) {
        B8v[b * 256 + t] = uint4{0u, 0u, 0u, 0u};
    } else {
        int e = (b - 2048) * 256 + t;
        atomicAdd(&rowcnt[ei[e]], 1);
    }
}

// ===== K2: exclusive prefix sum of rowcnt[4096] -> rowptr[4097] (single block) =====
__global__ __launch_bounds__(256) void prefix4096(const int* __restrict__ cnt,
                                                  int* __restrict__ ptr) {
    __shared__ int psum[256];
    int t = threadIdx.x;
    int loc[16];
    int s = 0;
    #pragma unroll
    for (int i = 0; i < 16; i++) { loc[i] = s; s += cnt[t * 16 + i]; }
    psum[t] = s;
    __syncthreads();
    if (t == 0) {
        int run = 0;
        for (int i = 0; i < 256; i++) { int v = psum[i]; psum[i] = run; run += v; }
        ptr[4096] = run;
    }
    __syncthreads();
    int off = psum[t];
    #pragma unroll
    for (int i = 0; i < 16; i++) ptr[t * 16 + i] = off + loc[i];
}

// ===== K3: scatter edges into CSR + accumulate d2[r] += rowcnt[c] =====
__global__ void k3_scatter_d2(const int* __restrict__ ei, const int* __restrict__ rowptr,
                              int* __restrict__ cursor, int* __restrict__ colidx,
                              const int* __restrict__ rowcnt, float* __restrict__ d2f) {
    int e = blockIdx.x * blockDim.x + threadIdx.x;
    int r = ei[e];
    int c = ei[NE + e];
    int p = atomicAdd(&cursor[r], 1);
    colidx[rowptr[r] + p] = c;
    atomicAdd(&d2f[r], (float)rowcnt[c]);
}

// ===== K4: score = tanh(pw0*(x.tr) + pw1*deg); d3 inline via CSR gather =====
__global__ __launch_bounds__(256) void k4_score(const float* __restrict__ x,
                                                const float* __restrict__ tr,
                                                const int* __restrict__ rowcnt,
                                                const float* __restrict__ d2f,
                                                const int* __restrict__ rowptr,
                                                const int* __restrict__ colidx,
                                                const float* __restrict__ fw,
                                                const float* __restrict__ pw,
                                                float* __restrict__ score) {
    int gtid = blockIdx.x * blockDim.x + threadIdx.x;
    int node = gtid >> 6;
    int lane = gtid & 63;
    const float* xr = x + (size_t)node * CH;
    float s = 0.f;
    #pragma unroll
    for (int q = 0; q < CH; q += 64) s += xr[q + lane] * tr[q + lane];
    int rs = rowptr[node], re = rowptr[node + 1];
    float dd = 0.f;                      // d3[node] = sum_{k in adj(node)} d2[k]
    for (int j = rs + lane; j < re; j += 64) dd += d2f[colidx[j]];
    #pragma unroll
    for (int off = 32; off > 0; off >>= 1) {
        s += __shfl_down(s, off);
        dd += __shfl_down(dd, off);
    }
    if (lane == 0) {
        float deg = fw[0] + fw[1] * (float)rowcnt[node] + fw[2] * d2f[node] + fw[3] * dd;
        score[node] = tanhf(pw[0] * s + pw[1] * deg);
    }
}

// ===== K5: stable descending argsort rank (== jnp stable argsort(-s)) =====
__global__ __launch_bounds__(256) void rank_kernel(const float* __restrict__ score,
                                                   int* __restrict__ rnk,
                                                   int* __restrict__ perm,
                                                   float* __restrict__ score_perm,
                                                   float* __restrict__ out_perm,
                                                   float* __restrict__ out_score) {
    __shared__ int wsum[4];
    int i = blockIdx.x;
    int t = threadIdx.x;
    float si = score[i];
    int cnt = 0;
    #pragma unroll
    for (int it = 0; it < NN / 4 / 256; it++) {
        int j4 = it * 256 + t;
        float4 s4 = reinterpret_cast<const float4*>(score)[j4];
        int j = j4 * 4;
        cnt += (int)((s4.x > si) | ((s4.x == si) & (j + 0 < i)));
        cnt += (int)((s4.y > si) | ((s4.y == si) & (j + 1 < i)));
        cnt += (int)((s4.z > si) | ((s4.z == si) & (j + 2 < i)));
        cnt += (int)((s4.w > si) | ((s4.w == si) & (j + 3 < i)));
    }
    #pragma unroll
    for (int off = 32; off > 0; off >>= 1) cnt += __shfl_down(cnt, off);
    if ((t & 63) == 0) wsum[t >> 6] = cnt;
    __syncthreads();
    if (t == 0) {
        int r = wsum[0] + wsum[1] + wsum[2] + wsum[3];
        rnk[i] = r;
        if (r < KSEL) {
            perm[r] = i;
            score_perm[r] = si;
            out_perm[r] = (float)i;
            out_score[r] = si;
        }
    }
}

// ===== K6: build B8[u,c]=A[u,perm[c]] (blocks 0..511) + xout (blocks 512..2559) =====
__global__ void k6_b8_xout(const int* __restrict__ ei, const int* __restrict__ rnk,
                           unsigned int* __restrict__ B32, const float* __restrict__ x,
                           const int* __restrict__ perm, const float* __restrict__ score_perm,
                           float* __restrict__ out_x) {
    int b = blockIdx.x;
    int t = threadIdx.x;
    if (b < 512) {
        int e = b * 256 + t;
        int rv = rnk[ei[NE + e]];
        if (rv < KSEL) {
            size_t idx = (size_t)ei[e] * KSEL + rv;
            atomicAdd(&B32[idx >> 2], 1u << ((idx & 3) * 8));
        }
    } else {
        int r = b - 512;
        out_x[(size_t)r * CH + t] = x[(size_t)perm[r] * CH + t] * score_perm[r];
    }
}

// ===== K7: B2[u,:] = sum_{k in adj(u)} B8[k,:]  (block-per-row, LDS-staged nb, uint2) =====
__global__ __launch_bounds__(256) void build_B2(const int* __restrict__ rowptr,
                                                const int* __restrict__ colidx,
                                                const unsigned char* __restrict__ B8,
                                                unsigned char* __restrict__ B2) {
    __shared__ int nb[128];
    int t = threadIdx.x;
    int u = blockIdx.x;
    int s = rowptr[u], e = rowptr[u + 1];
    int c8 = t * 8;
    unsigned sx = 0, sy = 0;
    for (int base = s; base < e; base += 128) {
        int n = min(128, e - base);
        __syncthreads();
        if (t < n) nb[t] = colidx[base + t];
        __syncthreads();
        #pragma unroll 4
        for (int i = 0; i < n; i++) {
            uint2 v = *(const uint2*)(B8 + (size_t)nb[i] * KSEL + c8);
            sx += v.x;
            sy += v.y;
        }
    }
    *(uint2*)(B2 + (size_t)u * KSEL + c8) = uint2{sx, sy};
}

// ===== K8: M_pool row r = w3*sum_{k in adj(pr)} B2[k,:] + w2*B2[pr,:] + w1*B8[pr,:] + w0*I =====
__global__ __launch_bounds__(256) void mpool_kernel(const int* __restrict__ rowptr,
                                                    const int* __restrict__ colidx,
                                                    const unsigned char* __restrict__ B8,
                                                    const unsigned char* __restrict__ B2,
                                                    const int* __restrict__ perm,
                                                    const float* __restrict__ fw,
                                                    float* __restrict__ Mpool) {
    __shared__ int nb[128];
    int t = threadIdx.x;
    int r = blockIdx.x;
    int pr = perm[r];
    int s = rowptr[pr], e = rowptr[pr + 1];
    int c8 = t * 8;
    unsigned a0 = 0, a1 = 0, a2 = 0, a3 = 0;   // u16x2 lanes (A^3 <= ~15K < 65535)
    for (int base = s; base < e; base += 128) {
        int n = min(128, e - base);
        __syncthreads();
        if (t < n) nb[t] = colidx[base + t];
        __syncthreads();
        #pragma unroll 4
        for (int i = 0; i < n; i++) {
            uint2 v = *(const uint2*)(B2 + (size_t)nb[i] * KSEL + c8);
            a0 += v.x & 0x00FF00FFu;
            a1 += (v.x >> 8) & 0x00FF00FFu;
            a2 += v.y & 0x00FF00FFu;
            a3 += (v.y >> 8) & 0x00FF00FFu;
        }
    }
    int sum[8];
    sum[0] = a0 & 0xFFFF; sum[2] = a0 >> 16;
    sum[1] = a1 & 0xFFFF; sum[3] = a1 >> 16;
    sum[4] = a2 & 0xFFFF; sum[6] = a2 >> 16;
    sum[5] = a3 & 0xFFFF; sum[7] = a3 >> 16;
    uint2 v2 = *(const uint2*)(B2 + (size_t)pr * KSEL + c8);
    uint2 v1 = *(const uint2*)(B8 + (size_t)pr * KSEL + c8);
    float w0 = fw[0], w1 = fw[1], w2 = fw[2], w3 = fw[3];
    int b2[8], b1[8];
    b2[0] = v2.x & 255;         b2[1] = (v2.x >> 8) & 255;
    b2[2] = (v2.x >> 16) & 255; b2[3] = v2.x >> 24;
    b2[4] = v2.y & 255;         b2[5] = (v2.y >> 8) & 255;
    b2[6] = (v2.y >> 16) & 255; b2[7] = v2.y >> 24;
    b1[0] = v1.x & 255;         b1[1] = (v1.x >> 8) & 255;
    b1[2] = (v1.x >> 16) & 255; b1[3] = v1.x >> 24;
    b1[4] = v1.y & 255;         b1[5] = (v1.y >> 8) & 255;
    b1[6] = (v1.y >> 16) & 255; b1[7] = v1.y >> 24;
    float o[8];
    #pragma unroll
    for (int j = 0; j < 8; j++) {
        o[j] = w3 * (float)sum[j] + w2 * (float)b2[j] + w1 * (float)b1[j]
             + ((c8 + j) == r ? w0 : 0.f);
    }
    float* dst = Mpool + (size_t)r * KSEL + c8;
    *(float4*)dst = float4{o[0], o[1], o[2], o[3]};
    *(float4*)(dst + 4) = float4{o[4], o[5], o[6], o[7]};
}

extern "C" void kernel_launch(void* const* d_in, const int* in_sizes, int n_in,
                              void* d_out, int out_size, void* d_ws, size_t ws_size,
                              hipStream_t stream) {
    const float* x  = (const float*)d_in[0];
    const int*   ei = (const int*)d_in[1];
    const float* tr = (const float*)d_in[2];
    const float* fw = (const float*)d_in[3];
    const float* pw = (const float*)d_in[4];

    float* out       = (float*)d_out;
    float* out_x     = out;
    float* out_M     = out + (size_t)KSEL * CH;
    float* out_perm  = out_M + (size_t)KSEL * KSEL;
    float* out_score = out_perm + KSEL;

    char* ws = (char*)d_ws;
    int*   rowcnt     = (int*)(ws);            // 16KB (zeroed)
    int*   cursor     = (int*)(ws + 16384);    // 16KB (zeroed)
    float* d2f        = (float*)(ws + 32768);  // 16KB (zeroed)
    float* score      = (float*)(ws + 65536);
    int*   rnk        = (int*)(ws + 81920);
    int*   perm       = (int*)(ws + 98304);    // 8KB
    float* score_perm = (float*)(ws + 106496); // 8KB
    int*   rowptr     = (int*)(ws + 131072);   // 4097 ints (32KB slot)
    int*   colidx     = (int*)(ws + 163840);   // 512KB
    unsigned char* B8 = (unsigned char*)(ws + 1048576);   // [1MB, 9MB)
    unsigned char* B2 = (unsigned char*)(ws + 9437184);   // [9MB, 17MB)

    (void)hipMemsetAsync(rowcnt, 0, 49152, stream);   // rowcnt, cursor, d2f

    k1_zero_count<<<2560, 256, 0, stream>>>(ei, (uint4*)B8, rowcnt);
    prefix4096<<<1, 256, 0, stream>>>(rowcnt, rowptr);
    k3_scatter_d2<<<512, 256, 0, stream>>>(ei, rowptr, cursor, colidx, rowcnt, d2f);
    k4_score<<<1024, 256, 0, stream>>>(x, tr, rowcnt, d2f, rowptr, colidx, fw, pw, score);
    rank_kernel<<<NN, 256, 0, stream>>>(score, rnk, perm, score_perm, out_perm, out_score);
    k6_b8_xout<<<2560, 256, 0, stream>>>(ei, rnk, (unsigned int*)B8, x, perm, score_perm, out_x);
    build_B2<<<NN, 256, 0, stream>>>(rowptr, colidx, B8, B2);
    mpool_kernel<<<KSEL, 256, 0, stream>>>(rowptr, colidx, B8, B2, perm, fw, out_M);
}